// Round 1
// baseline (27390.894 us; speedup 1.0000x reference)
//
#include <hip/hip_runtime.h>
#include <math.h>

#define T_STEPS 4096
#define HID     1024
#define G4      4096   // 4*HID gate rows
#define NB      64     // recurrence blocks (one per CU, all co-resident)

__device__ __forceinline__ unsigned ld_flag(unsigned* p) {
    return __hip_atomic_load(p, __ATOMIC_RELAXED, __HIP_MEMORY_SCOPE_AGENT);
}
__device__ __forceinline__ void st_flag(unsigned* p, unsigned v) {
    __hip_atomic_store(p, v, __ATOMIC_RELEASE, __HIP_MEMORY_SCOPE_AGENT);
}

// ---------------------------------------------------------------------------
// Kernel 1: xg[t][r] = dot(x[t,:], w_ih[r,:]) + b_ih[r] + b_hh[r]
// f32 GEMM, 64x64 tile, K-chunk 32, 256 threads, 4x4 per thread.
// Also zeroes the recurrence flags (block (0,0)) so each graph replay resets.
// ---------------------------------------------------------------------------
__global__ __launch_bounds__(256) void xg_gemm(
    const float* __restrict__ x, const float* __restrict__ w_ih,
    const float* __restrict__ b_ih, const float* __restrict__ b_hh,
    float* __restrict__ xg, unsigned* __restrict__ flags)
{
    if (blockIdx.x == 0 && blockIdx.y == 0 && threadIdx.x < NB)
        flags[threadIdx.x] = 0u;

    __shared__ float Xs[32][68];   // [k][m], row = 272B (16B aligned), pad kills conflicts
    __shared__ float Ws[32][68];   // [k][n]

    const int t0  = blockIdx.y * 64;
    const int n0  = blockIdx.x * 64;
    const int thr = threadIdx.x;
    const int tx  = thr & 15;      // n-group
    const int ty  = thr >> 4;      // m-group

    float acc[4][4] = {};

    for (int kk = 0; kk < 1024; kk += 32) {
        #pragma unroll
        for (int i = 0; i < 2; i++) {
            int flat = thr + i * 256;       // 0..511
            int m    = flat >> 3;           // 0..63
            int kc   = flat & 7;            // k-chunk (4 floats)
            float4 xv = *(const float4*)(x    + (size_t)(t0 + m) * 1024 + kk + kc * 4);
            float4 wv = *(const float4*)(w_ih + (size_t)(n0 + m) * 1024 + kk + kc * 4);
            Xs[kc*4+0][m] = xv.x; Xs[kc*4+1][m] = xv.y;
            Xs[kc*4+2][m] = xv.z; Xs[kc*4+3][m] = xv.w;
            Ws[kc*4+0][m] = wv.x; Ws[kc*4+1][m] = wv.y;
            Ws[kc*4+2][m] = wv.z; Ws[kc*4+3][m] = wv.w;
        }
        __syncthreads();
        #pragma unroll
        for (int k = 0; k < 32; k++) {
            float4 a4 = *(const float4*)&Xs[k][ty * 4];
            float4 b4 = *(const float4*)&Ws[k][tx * 4];
            float av[4] = {a4.x, a4.y, a4.z, a4.w};
            float bv[4] = {b4.x, b4.y, b4.z, b4.w};
            #pragma unroll
            for (int i = 0; i < 4; i++)
                #pragma unroll
                for (int j = 0; j < 4; j++)
                    acc[i][j] = fmaf(av[i], bv[j], acc[i][j]);
        }
        __syncthreads();
    }

    float4 bi = *(const float4*)(b_ih + n0 + tx * 4);
    float4 bh = *(const float4*)(b_hh + n0 + tx * 4);
    float bb[4] = {bi.x + bh.x, bi.y + bh.y, bi.z + bh.z, bi.w + bh.w};
    #pragma unroll
    for (int i = 0; i < 4; i++) {
        float4 o;
        o.x = acc[i][0] + bb[0]; o.y = acc[i][1] + bb[1];
        o.z = acc[i][2] + bb[2]; o.w = acc[i][3] + bb[3];
        *(float4*)(xg + (size_t)(t0 + ty * 4 + i) * G4 + n0 + tx * 4) = o;
    }
}

// ---------------------------------------------------------------------------
// Kernel 2: persistent recurrence. 64 blocks x 1024 threads, all co-resident.
// Block b owns hidden units [b*16, b*16+16) -> 64 gate rows.
// W_hh slice lives in registers: thread (rg,ec) holds 4 rows x 16 elems.
// Per step: poll flags -> stage h (4KB) to LDS -> dot+wave reduce ->
//           gate update (lanes<16, c in registers) -> release h + flag.
// ---------------------------------------------------------------------------
__global__ __launch_bounds__(1024, 4) void lstm_rec(
    const float* __restrict__ xg, const float* __restrict__ w_hh,
    const float* __restrict__ h0, const float* __restrict__ c0,
    const float* __restrict__ w_out, const float* __restrict__ b_out,
    float* h_buf,            // [2][HID]
    unsigned* flags,         // [NB]
    float* out)
{
    __shared__ float h_lds[64 * 20];   // 64 chunks of 16 floats, stride 20 (80B, 16B aligned)
    __shared__ float g_lds[64];        // gate preacts for this block's 64 rows

    const int thr = threadIdx.x;
    const int b   = blockIdx.x;
    const int rg  = thr >> 6;          // row-group 0..15 (== wave id)
    const int ec  = thr & 63;          // elem-chunk 0..63 (== lane)

    // row-slot s in [0,64): gate = s>>4, unit_local = s&15
    // this thread's 4 rows: s = rg*4 + rr
    int grow[4];
    #pragma unroll
    for (int rr = 0; rr < 4; rr++) {
        int s = rg * 4 + rr;
        grow[rr] = (s >> 4) * HID + b * 16 + (s & 15);
    }

    // ---- preload weights into registers: w[rr*16+j] = w_hh[grow[rr]][ec*16+j]
    float w[64];
    #pragma unroll
    for (int rr = 0; rr < 4; rr++) {
        const float* wr = w_hh + (size_t)grow[rr] * HID + ec * 16;
        #pragma unroll
        for (int j4 = 0; j4 < 4; j4++) {
            float4 v = *(const float4*)(wr + j4 * 4);
            w[rr*16 + j4*4 + 0] = v.x; w[rr*16 + j4*4 + 1] = v.y;
            w[rr*16 + j4*4 + 2] = v.z; w[rr*16 + j4*4 + 3] = v.w;
        }
    }

    // ---- init: c in registers of lanes 0..15 of wave 0; publish h0 slice
    float c = 0.0f;
    if (thr < 16) {
        c = c0[b * 16 + thr];
        h_buf[b * 16 + thr] = h0[b * 16 + thr];
    }
    if (thr < 64) {
        __threadfence();
        if (thr == 0) st_flag(&flags[b], 1u);
    }

    // ---- main loop
    for (int t = 0; t < T_STEPS; t++) {
        const int p = t & 1;

        // xg prefetch (independent of flags): lanes 0..3 of each wave
        float xgv = 0.0f;
        if (ec < 4) xgv = xg[(size_t)t * G4 + grow[ec]];

        // wave 0 polls all 64 block flags (one lane per block)
        if (thr < 64) {
            const unsigned target = (unsigned)(t + 1);
            while (!__all(ld_flag(&flags[thr]) >= target)) { }
            __threadfence();   // acquire: invalidate L1/L2 before h reads
        }
        __syncthreads();

        // stage h -> LDS (padded chunks)
        float hval = h_buf[p * HID + thr];
        h_lds[(thr >> 4) * 20 + (thr & 15)] = hval;
        __syncthreads();

        // dot: 4 rows x 16 elems per thread
        float4 hv0 = *(const float4*)&h_lds[ec * 20 + 0];
        float4 hv1 = *(const float4*)&h_lds[ec * 20 + 4];
        float4 hv2 = *(const float4*)&h_lds[ec * 20 + 8];
        float4 hv3 = *(const float4*)&h_lds[ec * 20 + 12];
        float hx[16] = {hv0.x,hv0.y,hv0.z,hv0.w, hv1.x,hv1.y,hv1.z,hv1.w,
                        hv2.x,hv2.y,hv2.z,hv2.w, hv3.x,hv3.y,hv3.z,hv3.w};
        float accr[4] = {0.f, 0.f, 0.f, 0.f};
        #pragma unroll
        for (int rr = 0; rr < 4; rr++)
            #pragma unroll
            for (int j = 0; j < 16; j++)
                accr[rr] = fmaf(w[rr*16 + j], hx[j], accr[rr]);

        // butterfly reduce across the 64 lanes of this wave (all lanes end with full sums)
        #pragma unroll
        for (int m = 1; m < 64; m <<= 1) {
            accr[0] += __shfl_xor(accr[0], m, 64);
            accr[1] += __shfl_xor(accr[1], m, 64);
            accr[2] += __shfl_xor(accr[2], m, 64);
            accr[3] += __shfl_xor(accr[3], m, 64);
        }
        // lanes 0..3 write their row's preact (+xg)
        if (ec < 4) {
            float r = (ec == 0) ? accr[0] : (ec == 1) ? accr[1]
                    : (ec == 2) ? accr[2] : accr[3];
            g_lds[rg * 4 + ec] = r + xgv;
        }
        __syncthreads();

        // gate update: lanes 0..15 of wave 0 own one hidden unit each
        if (thr < 16) {
            float gi = g_lds[thr];
            float gf = g_lds[16 + thr];
            float gg = g_lds[32 + thr];
            float go = g_lds[48 + thr];
            float si = 1.0f / (1.0f + expf(-gi));
            float sf = 1.0f / (1.0f + expf(-gf));
            float tg = tanhf(gg);
            float so = 1.0f / (1.0f + expf(-go));
            c = sf * c + si * tg;
            float hn = so * tanhf(c);
            h_buf[(p ^ 1) * HID + b * 16 + thr] = hn;
        }
        if (thr < 64) {
            __threadfence();   // release: drain h stores, write back L2
            if (thr == 0) st_flag(&flags[b], (unsigned)(t + 2));
        }
    }

    // ---- tail: block 0 computes pred = tanh(w_out . h_final + b_out)
    if (b == 0) {
        if (thr < 64) {
            const unsigned target = (unsigned)(T_STEPS + 1);
            while (!__all(ld_flag(&flags[thr]) >= target)) { }
            __threadfence();
        }
        __syncthreads();
        if (thr < 64) {
            // h_{4095} lives in h_buf[ (4095+1)&1 ] = h_buf[0]
            float a = 0.0f;
            #pragma unroll
            for (int i = 0; i < 16; i++)
                a = fmaf(h_buf[0 * HID + thr * 16 + i], w_out[thr * 16 + i], a);
            #pragma unroll
            for (int m = 1; m < 64; m <<= 1)
                a += __shfl_xor(a, m, 64);
            if (thr == 0) out[0] = tanhf(a + b_out[0]);
        }
    }
}

// ---------------------------------------------------------------------------
extern "C" void kernel_launch(void* const* d_in, const int* in_sizes, int n_in,
                              void* d_out, int out_size, void* d_ws, size_t ws_size,
                              hipStream_t stream) {
    const float* x     = (const float*)d_in[0];
    const float* h0    = (const float*)d_in[1];
    const float* c0    = (const float*)d_in[2];
    const float* w_ih  = (const float*)d_in[3];
    const float* w_hh  = (const float*)d_in[4];
    const float* b_ih  = (const float*)d_in[5];
    const float* b_hh  = (const float*)d_in[6];
    const float* w_out = (const float*)d_in[7];
    const float* b_out = (const float*)d_in[8];
    float* out = (float*)d_out;

    char* ws = (char*)d_ws;
    float*    xg    = (float*)ws;                                   // 64 MiB
    float*    h_buf = (float*)(ws + (size_t)T_STEPS * G4 * 4);      // 8 KiB
    unsigned* flags = (unsigned*)(ws + (size_t)T_STEPS * G4 * 4 + 2 * HID * 4);

    xg_gemm<<<dim3(64, 64), 256, 0, stream>>>(x, w_ih, b_ih, b_hh, xg, flags);
    lstm_rec<<<NB, 1024, 0, stream>>>(xg, w_hh, h0, c0, w_out, b_out,
                                      h_buf, flags, out);
}

// Round 2
// 8750.649 us; speedup vs baseline: 3.1302x; 3.1302x over previous
//
#include <hip/hip_runtime.h>
#include <math.h>

#define T_STEPS 4096
#define HID     1024
#define G4      4096   // 4*HID gate rows
#define NB      64     // recurrence blocks (one per CU, all co-resident)

// ---- tagged-word publish: one 64-bit atomic = {u32 step-tag | f32 value} ----
__device__ __forceinline__ unsigned long long ld64(const unsigned long long* p) {
    return __hip_atomic_load(p, __ATOMIC_RELAXED, __HIP_MEMORY_SCOPE_AGENT);
}
__device__ __forceinline__ void st64(unsigned long long* p, unsigned long long v) {
    __hip_atomic_store(p, v, __ATOMIC_RELAXED, __HIP_MEMORY_SCOPE_AGENT);
}
__device__ __forceinline__ unsigned long long packhv(float h, unsigned tag) {
    return ((unsigned long long)tag << 32) | (unsigned long long)__float_as_uint(h);
}

// ---------------------------------------------------------------------------
// Kernel 1: xg[t][r] = dot(x[t,:], w_ih[r,:]) + b_ih[r] + b_hh[r]
// f32 GEMM, 64x64 tile, K-chunk 32, 256 threads, 4x4 per thread.
// Blocks (0, y<8) also zero h_pub (2x1024 u64) so each graph replay resets.
// ---------------------------------------------------------------------------
__global__ __launch_bounds__(256) void xg_gemm(
    const float* __restrict__ x, const float* __restrict__ w_ih,
    const float* __restrict__ b_ih, const float* __restrict__ b_hh,
    float* __restrict__ xg, unsigned long long* __restrict__ h_pub)
{
    if (blockIdx.x == 0 && blockIdx.y < 8)
        h_pub[blockIdx.y * 256 + threadIdx.x] = 0ull;

    __shared__ float Xs[32][68];   // [k][m], pad kills conflicts
    __shared__ float Ws[32][68];   // [k][n]

    const int t0  = blockIdx.y * 64;
    const int n0  = blockIdx.x * 64;
    const int thr = threadIdx.x;
    const int tx  = thr & 15;      // n-group
    const int ty  = thr >> 4;      // m-group

    float acc[4][4] = {};

    for (int kk = 0; kk < 1024; kk += 32) {
        #pragma unroll
        for (int i = 0; i < 2; i++) {
            int flat = thr + i * 256;       // 0..511
            int m    = flat >> 3;           // 0..63
            int kc   = flat & 7;            // k-chunk (4 floats)
            float4 xv = *(const float4*)(x    + (size_t)(t0 + m) * 1024 + kk + kc * 4);
            float4 wv = *(const float4*)(w_ih + (size_t)(n0 + m) * 1024 + kk + kc * 4);
            Xs[kc*4+0][m] = xv.x; Xs[kc*4+1][m] = xv.y;
            Xs[kc*4+2][m] = xv.z; Xs[kc*4+3][m] = xv.w;
            Ws[kc*4+0][m] = wv.x; Ws[kc*4+1][m] = wv.y;
            Ws[kc*4+2][m] = wv.z; Ws[kc*4+3][m] = wv.w;
        }
        __syncthreads();
        #pragma unroll
        for (int k = 0; k < 32; k++) {
            float4 a4 = *(const float4*)&Xs[k][ty * 4];
            float4 b4 = *(const float4*)&Ws[k][tx * 4];
            float av[4] = {a4.x, a4.y, a4.z, a4.w};
            float bv[4] = {b4.x, b4.y, b4.z, b4.w};
            #pragma unroll
            for (int i = 0; i < 4; i++)
                #pragma unroll
                for (int j = 0; j < 4; j++)
                    acc[i][j] = fmaf(av[i], bv[j], acc[i][j]);
        }
        __syncthreads();
    }

    float4 bi = *(const float4*)(b_ih + n0 + tx * 4);
    float4 bh = *(const float4*)(b_hh + n0 + tx * 4);
    float bb[4] = {bi.x + bh.x, bi.y + bh.y, bi.z + bh.z, bi.w + bh.w};
    #pragma unroll
    for (int i = 0; i < 4; i++) {
        float4 o;
        o.x = acc[i][0] + bb[0]; o.y = acc[i][1] + bb[1];
        o.z = acc[i][2] + bb[2]; o.w = acc[i][3] + bb[3];
        *(float4*)(xg + (size_t)(t0 + ty * 4 + i) * G4 + n0 + tx * 4) = o;
    }
}

// ---------------------------------------------------------------------------
// Kernel 2: persistent recurrence. 64 blocks x 512 threads (8 waves).
// Block b owns hidden units [b*16, b*16+16) -> 64 gate rows.
// Wave rg owns rows s = rg*8 .. rg*8+7; lane ec owns cols [ec*16, ec*16+16).
// Weights live in registers: float4 w[8][4] per thread (128 floats).
// Per step: spin on tagged h words (1 IF round trip) -> LDS stage ->
//           8x16 dot -> 10-shuffle multi-value fold -> gates (lanes<16) ->
//           fire-and-forget tagged publish. No fences anywhere.
// ---------------------------------------------------------------------------
__global__ __launch_bounds__(512, 2) void lstm_rec(
    const float* __restrict__ xg, const float* __restrict__ w_hh,
    const float* __restrict__ h0, const float* __restrict__ c0,
    const float* __restrict__ w_out, const float* __restrict__ b_out,
    unsigned long long* __restrict__ h_pub,   // [2][HID] tagged words
    float* __restrict__ out)
{
    __shared__ float h_lds[64 * 20];   // 64 chunks of 16 floats, stride 20
    __shared__ float g_lds[64];        // gate preacts for this block's 64 rows

    const int thr = threadIdx.x;
    const int b   = blockIdx.x;
    const int rg  = thr >> 6;          // wave 0..7
    const int ec  = thr & 63;          // lane 0..63

    // ---- preload weights: rows s = rg*8+rr, cols ec*16..+15
    float4 w[8][4];
    #pragma unroll
    for (int rr = 0; rr < 8; rr++) {
        const int s = rg * 8 + rr;
        const float* wr = w_hh + (size_t)((s >> 4) * HID + b * 16 + (s & 15)) * HID + ec * 16;
        #pragma unroll
        for (int q = 0; q < 4; q++)
            w[rr][q] = *(const float4*)(wr + q * 4);
    }

    // ---- init: c in registers of lanes 0..15 of wave 0; publish h0 (tag 1)
    float c = 0.0f;
    if (thr < 16) {
        c = c0[b * 16 + thr];
        st64(&h_pub[0 * HID + b * 16 + thr], packhv(h0[b * 16 + thr], 1u));
    }

    const int u0 = 2 * thr;            // this thread's two h units (contiguous)
    const int l0 = (u0 >> 4) * 20 + (u0 & 15);

    for (int t = 0; t < T_STEPS; t++) {
        const int p = t & 1;

        // xg prefetch (independent of the handoff): lanes ec<8, row rg*8+ec
        const int sx = rg * 8 + (ec & 7);
        float xgv = (ec < 8)
            ? xg[(size_t)t * G4 + (sx >> 4) * HID + b * 16 + (sx & 15)] : 0.0f;

        // ---- spin on own two tagged words (single IF round trip per poll)
        const unsigned tag = (unsigned)(t + 1);
        const unsigned long long* a0 = &h_pub[p * HID + u0];
        unsigned long long v0 = ld64(a0), v1 = ld64(a0 + 1);
        while (((unsigned)(v0 >> 32) != tag) | ((unsigned)(v1 >> 32) != tag)) {
            v0 = ld64(a0); v1 = ld64(a0 + 1);
        }
        h_lds[l0]     = __uint_as_float((unsigned)v0);
        h_lds[l0 + 1] = __uint_as_float((unsigned)v1);
        __syncthreads();

        // ---- dot: 8 rows x 16 elems per thread
        float4 h4[4];
        #pragma unroll
        for (int q = 0; q < 4; q++)
            h4[q] = *(const float4*)&h_lds[ec * 20 + q * 4];

        float a[8];
        #pragma unroll
        for (int rr = 0; rr < 8; rr++) {
            float s0 = 0.f, s1 = 0.f, s2 = 0.f, s3 = 0.f;
            #pragma unroll
            for (int q = 0; q < 4; q++) {
                s0 = fmaf(w[rr][q].x, h4[q].x, s0);
                s1 = fmaf(w[rr][q].y, h4[q].y, s1);
                s2 = fmaf(w[rr][q].z, h4[q].z, s2);
                s3 = fmaf(w[rr][q].w, h4[q].w, s3);
            }
            a[rr] = (s0 + s1) + (s2 + s3);
        }

        // ---- multi-value fold: 8 accs x 64 lanes -> lane holds row (lane&7)
        const bool b0 = (ec & 1), b1 = (ec & 2), b2 = (ec & 4);
        float f[4];
        #pragma unroll
        for (int i = 0; i < 4; i++) {
            float send = b0 ? a[2*i] : a[2*i+1];
            float recv = __shfl_xor(send, 1, 64);
            f[i] = (b0 ? a[2*i+1] : a[2*i]) + recv;
        }
        float g2[2];
        #pragma unroll
        for (int i = 0; i < 2; i++) {
            float send = b1 ? f[2*i] : f[2*i+1];
            float recv = __shfl_xor(send, 2, 64);
            g2[i] = (b1 ? f[2*i+1] : f[2*i]) + recv;
        }
        float d;
        {
            float send = b2 ? g2[0] : g2[1];
            float recv = __shfl_xor(send, 4, 64);
            d = (b2 ? g2[1] : g2[0]) + recv;
        }
        d += __shfl_xor(d, 8, 64);
        d += __shfl_xor(d, 16, 64);
        d += __shfl_xor(d, 32, 64);

        if (ec < 8) g_lds[rg * 8 + ec] = d + xgv;
        __syncthreads();

        // ---- gate update: lanes 0..15 of wave 0 own one hidden unit each
        if (thr < 16) {
            float gi = g_lds[thr];
            float gf = g_lds[16 + thr];
            float gg = g_lds[32 + thr];
            float go = g_lds[48 + thr];
            float si = 1.0f / (1.0f + expf(-gi));
            float sf = 1.0f / (1.0f + expf(-gf));
            float tg = tanhf(gg);
            float so = 1.0f / (1.0f + expf(-go));
            c = sf * c + si * tg;
            float hn = so * tanhf(c);
            // fire-and-forget publish: word is self-validating
            st64(&h_pub[(p ^ 1) * HID + b * 16 + thr], packhv(hn, (unsigned)(t + 2)));
        }
        // no trailing barrier: next-iteration barrier orders LDS reuse
    }

    // ---- tail: block 0 computes pred = tanh(w_out . h_final + b_out)
    if (b == 0) {
        const unsigned tag = (unsigned)(T_STEPS + 1);    // h_4096 in buffer 0
        const unsigned long long* a0 = &h_pub[0 * HID + u0];
        unsigned long long v0 = ld64(a0), v1 = ld64(a0 + 1);
        while (((unsigned)(v0 >> 32) != tag) | ((unsigned)(v1 >> 32) != tag)) {
            v0 = ld64(a0); v1 = ld64(a0 + 1);
        }
        float part = __uint_as_float((unsigned)v0) * w_out[u0]
                   + __uint_as_float((unsigned)v1) * w_out[u0 + 1];
        #pragma unroll
        for (int m = 1; m < 64; m <<= 1)
            part += __shfl_xor(part, m, 64);
        __syncthreads();
        if (ec == 0) g_lds[rg] = part;
        __syncthreads();
        if (thr == 0) {
            float s = 0.f;
            #pragma unroll
            for (int i = 0; i < 8; i++) s += g_lds[i];
            out[0] = tanhf(s + b_out[0]);
        }
    }
}

// ---------------------------------------------------------------------------
extern "C" void kernel_launch(void* const* d_in, const int* in_sizes, int n_in,
                              void* d_out, int out_size, void* d_ws, size_t ws_size,
                              hipStream_t stream) {
    const float* x     = (const float*)d_in[0];
    const float* h0    = (const float*)d_in[1];
    const float* c0    = (const float*)d_in[2];
    const float* w_ih  = (const float*)d_in[3];
    const float* w_hh  = (const float*)d_in[4];
    const float* b_ih  = (const float*)d_in[5];
    const float* b_hh  = (const float*)d_in[6];
    const float* w_out = (const float*)d_in[7];
    const float* b_out = (const float*)d_in[8];
    float* out = (float*)d_out;

    char* ws = (char*)d_ws;
    float*              xg    = (float*)ws;                               // 64 MiB
    unsigned long long* h_pub = (unsigned long long*)(ws + (size_t)T_STEPS * G4 * 4);  // 16 KiB

    xg_gemm<<<dim3(64, 64), 256, 0, stream>>>(x, w_ih, b_ih, b_hh, xg, h_pub);
    lstm_rec<<<NB, 512, 0, stream>>>(xg, w_hh, h0, c0, w_out, b_out, h_pub, out);
}